// Round 1
// baseline (249.287 us; speedup 1.0000x reference)
//
#include <hip/hip_runtime.h>
#include <hip/hip_bf16.h>

// Problem constants (T, H, O) = (32768, 1024, 1024)
constexpr int T = 32768;
constexpr int H = 1024;
constexpr int NB = 512;          // blocks in weighted pass
constexpr int RPB = T / NB;      // rows per block = 64

// ws layout (floats): [0]=M, [1]=L, [64 .. 64+T) = scores, [64+T ...) = partials (NB*H)
constexpr int SC_OFF = 64;
constexpr int PART_OFF = SC_OFF + T;

// ---------------- Kernel A: scores[t] = dot(enc[t], w_enc) ----------------
// One wave (64 lanes) per row. Lane i reads float4 at i + p*64.
__global__ void scores_kernel(const float* __restrict__ enc,
                              const float* __restrict__ w_enc,
                              float* __restrict__ scores) {
    const int gwave = (blockIdx.x * blockDim.x + threadIdx.x) >> 6;
    const int lane  = threadIdx.x & 63;
    if (gwave >= T) return;
    const float4* rowp = reinterpret_cast<const float4*>(enc + (size_t)gwave * H);
    const float4* wp   = reinterpret_cast<const float4*>(w_enc);
    float acc = 0.f;
#pragma unroll
    for (int p = 0; p < H / (64 * 4); ++p) {
        float4 e = rowp[lane + p * 64];
        float4 w = wp[lane + p * 64];
        acc += e.x * w.x + e.y * w.y + e.z * w.z + e.w * w.w;
    }
#pragma unroll
    for (int off = 32; off; off >>= 1) acc += __shfl_down(acc, off);
    if (lane == 0) scores[gwave] = acc;
}

// ---------------- Kernel B: global max + sum(exp), zero out vector ----------------
__global__ void reduce_ml(const float* __restrict__ sc,
                          float* __restrict__ ml,
                          float* __restrict__ outvec) {
    __shared__ float sm[16];
    const int tid = threadIdx.x;          // 1024 threads, 16 waves
    if (tid < H) outvec[tid] = 0.f;       // (unused by finalize path, kept for safety)

    float m = -1e30f;
    for (int t = tid; t < T; t += 1024) m = fmaxf(m, sc[t]);
#pragma unroll
    for (int off = 32; off; off >>= 1) m = fmaxf(m, __shfl_down(m, off));
    if ((tid & 63) == 0) sm[tid >> 6] = m;
    __syncthreads();
    if (tid < 16) {
        float v = sm[tid];
#pragma unroll
        for (int off = 8; off; off >>= 1) v = fmaxf(v, __shfl_down(v, off));
        if (tid == 0) sm[0] = v;
    }
    __syncthreads();
    const float M = sm[0];
    __syncthreads();

    float l = 0.f;
    for (int t = tid; t < T; t += 1024) l += expf(sc[t] - M);
#pragma unroll
    for (int off = 32; off; off >>= 1) l += __shfl_down(l, off);
    if ((tid & 63) == 0) sm[tid >> 6] = l;
    __syncthreads();
    if (tid == 0) {
        float L = 0.f;
#pragma unroll
        for (int i = 0; i < 16; ++i) L += sm[i];
        ml[0] = M;
        ml[1] = L;
    }
}

// ---------------- Kernel C: weights out + partial weighted sums ----------------
// 256 threads/block; thread owns 4 output columns (float4). RPB rows per block.
__global__ void weighted_kernel(const float* __restrict__ enc,
                                const float* __restrict__ sc,
                                const float* __restrict__ ml,
                                float* __restrict__ wout,
                                float* __restrict__ partials) {
    const int b = blockIdx.x;
    const int tid = threadIdx.x;
    const float M = ml[0];
    const float rL = 1.f / ml[1];
    const int row0 = b * RPB;

    // coalesced normalized-weight write (wave 0)
    if (tid < RPB) wout[row0 + tid] = expf(sc[row0 + tid] - M) * rL;

    float4 acc = make_float4(0.f, 0.f, 0.f, 0.f);
#pragma unroll 4
    for (int r = 0; r < RPB; ++r) {
        const size_t row = (size_t)(row0 + r);
        const float w = expf(sc[row] - M) * rL;   // broadcast load, redundant exp (cheap)
        float4 e = *reinterpret_cast<const float4*>(enc + row * H + (size_t)tid * 4);
        acc.x = fmaf(w, e.x, acc.x);
        acc.y = fmaf(w, e.y, acc.y);
        acc.z = fmaf(w, e.z, acc.z);
        acc.w = fmaf(w, e.w, acc.w);
    }
    *reinterpret_cast<float4*>(partials + (size_t)b * H + (size_t)tid * 4) = acc;
}

// ---------------- Kernel D: reduce partials -> out[0..H) ----------------
__global__ void finalize_kernel(const float* __restrict__ partials,
                                float* __restrict__ out) {
    const int h = blockIdx.x * blockDim.x + threadIdx.x;   // 1024 threads total
    float s = 0.f;
#pragma unroll 8
    for (int b = 0; b < NB; ++b) s += partials[(size_t)b * H + h];
    out[h] = s;
}

extern "C" void kernel_launch(void* const* d_in, const int* in_sizes, int n_in,
                              void* d_out, int out_size, void* d_ws, size_t ws_size,
                              hipStream_t stream) {
    // inputs: dec_h (1024), enc (T*H), attn_w (2048), attn_b (1)
    const float* enc    = (const float*)d_in[1];
    const float* attn_w = (const float*)d_in[2];
    const float* w_enc  = attn_w + 1024;     // attn_w[:, O:] — the enc half

    float* out  = (float*)d_out;             // [0..1024): output vector
    float* wout = (float*)d_out + H;         // [1024..1024+T): normalized weights

    float* ws       = (float*)d_ws;
    float* ml       = ws;                    // M, L
    float* scores   = ws + SC_OFF;
    float* partials = ws + PART_OFF;

    // A: 32768 waves, 4 waves/block -> 8192 blocks
    scores_kernel<<<T / 4, 256, 0, stream>>>(enc, w_enc, scores);
    // B: single block computes M, L
    reduce_ml<<<1, 1024, 0, stream>>>(scores, ml, out);
    // C: weights + partial output sums
    weighted_kernel<<<NB, 256, 0, stream>>>(enc, scores, ml, wout, partials);
    // D: final output vector
    finalize_kernel<<<H / 256, 256, 0, stream>>>(partials, out);
}

// Round 2
// 209.869 us; speedup vs baseline: 1.1878x; 1.1878x over previous
//
#include <hip/hip_runtime.h>
#include <hip/hip_bf16.h>

// (T, H, O) = (32768, 1024, 1024)
constexpr int T = 32768;
constexpr int H = 1024;

constexpr int NB1 = 1024;          // blocks in fused pass 1
constexpr int RPB = T / NB1;       // rows per block = 32
constexpr int CH  = 8;             // rows per chunk (register-resident)

// ws layout (floats)
constexpr int ML_OFF  = 0;                 // [0]=M, [1]=1/L
constexpr int MB_OFF  = 256;               // per-block running max  (NB1)
constexpr int LB_OFF  = MB_OFF + NB1;      // per-block running sum  (NB1)
constexpr int SC_OFF  = 4096;              // raw scores (T)
constexpr int ACC_OFF = SC_OFF + T;        // per-block partial outputs (NB1*H)

// ---------------- Kernel 1: fused scores + online-softmax partial output ----
// 256 threads/block. Thread t owns output columns 4t..4t+3. Block owns 32 rows.
// Each enc element is read from HBM exactly once (held in registers for both
// the dot product and the weighted accumulation).
__global__ __launch_bounds__(256) void fused_pass1(
    const float* __restrict__ enc, const float* __restrict__ w_enc,
    float* __restrict__ scores, float* __restrict__ mb, float* __restrict__ lb,
    float* __restrict__ accs) {
    const int b    = blockIdx.x;
    const int tid  = threadIdx.x;
    const int wave = tid >> 6;
    const int lane = tid & 63;
    const int row0 = b * RPB;

    const float4 w4 = *reinterpret_cast<const float4*>(w_enc + 4 * tid);

    __shared__ float red[4][CH];

    float  m = -1e30f, l = 0.f;
    float4 acc = make_float4(0.f, 0.f, 0.f, 0.f);

    for (int c = 0; c < RPB / CH; ++c) {
        const int r0 = row0 + c * CH;
        float4 e[CH];
        float  p[CH];
#pragma unroll
        for (int r = 0; r < CH; ++r) {
            e[r] = *reinterpret_cast<const float4*>(enc + (size_t)(r0 + r) * H + 4 * tid);
            p[r] = e[r].x * w4.x + e[r].y * w4.y + e[r].z * w4.z + e[r].w * w4.w;
        }
        // wave-level butterfly: every lane gets the wave-sum of each row-partial
#pragma unroll
        for (int r = 0; r < CH; ++r) {
#pragma unroll
            for (int off = 32; off; off >>= 1) p[r] += __shfl_xor(p[r], off);
        }
        if (lane == 0) {
#pragma unroll
            for (int r = 0; r < CH; ++r) red[wave][r] = p[r];
        }
        __syncthreads();
        float s[CH];
        float mc = -1e30f;
#pragma unroll
        for (int r = 0; r < CH; ++r) {
            s[r] = red[0][r] + red[1][r] + red[2][r] + red[3][r];
            mc = fmaxf(mc, s[r]);
        }
        __syncthreads();   // red reusable next chunk

        const float mn  = fmaxf(m, mc);
        const float rs  = __expf(m - mn);     // m=-1e30 first pass -> 0
        l *= rs;
        acc.x *= rs; acc.y *= rs; acc.z *= rs; acc.w *= rs;
#pragma unroll
        for (int r = 0; r < CH; ++r) {
            const float wgt = __expf(s[r] - mn);
            l += wgt;
            acc.x = fmaf(wgt, e[r].x, acc.x);
            acc.y = fmaf(wgt, e[r].y, acc.y);
            acc.z = fmaf(wgt, e[r].z, acc.z);
            acc.w = fmaf(wgt, e[r].w, acc.w);
        }
        m = mn;

        if (tid == 0) {
#pragma unroll
            for (int r = 0; r < CH; ++r) scores[r0 + r] = s[r];
        }
    }

    *reinterpret_cast<float4*>(accs + (size_t)b * H + 4 * tid) = acc;
    if (tid == 0) { mb[b] = m; lb[b] = l; }
}

// ---------------- Kernel 2: global M, L from per-block (m,l); zero out ------
__global__ __launch_bounds__(1024) void reduce2(
    const float* __restrict__ mb, const float* __restrict__ lb,
    float* __restrict__ ml, float* __restrict__ out) {
    __shared__ float sm[16];
    const int tid  = threadIdx.x;          // 1024 == NB1
    const int wave = tid >> 6;
    const int lane = tid & 63;

    out[tid] = 0.f;                        // d_out[0..H) zero-init (poisoned 0xAA)

    const float mv = mb[tid];
    float m = mv;
#pragma unroll
    for (int off = 32; off; off >>= 1) m = fmaxf(m, __shfl_xor(m, off));
    if (lane == 0) sm[wave] = m;
    __syncthreads();
    if (tid < 64) {
        float v = (lane < 16) ? sm[lane] : -1e30f;
#pragma unroll
        for (int off = 8; off; off >>= 1) v = fmaxf(v, __shfl_xor(v, off));
        if (tid == 0) sm[0] = v;
    }
    __syncthreads();
    const float M = sm[0];
    __syncthreads();

    float lv = lb[tid] * __expf(mv - M);
#pragma unroll
    for (int off = 32; off; off >>= 1) lv += __shfl_xor(lv, off);
    if (lane == 0) sm[wave] = lv;
    __syncthreads();
    if (tid == 0) {
        float L = 0.f;
#pragma unroll
        for (int i = 0; i < 16; ++i) L += sm[i];
        ml[0] = M;
        ml[1] = 1.f / L;
    }
}

// ---------------- Kernel 3: combine partials (atomic) + weights output ------
// blocks 0..63: out[h] += sum over 16 partial vectors, rescaled
// blocks 64..95: normalized weights for 1024 t-values each
__global__ __launch_bounds__(256) void combine3(
    const float* __restrict__ mb, const float* __restrict__ accs,
    const float* __restrict__ scores, const float* __restrict__ ml,
    float* __restrict__ out, float* __restrict__ wout) {
    const int tid = threadIdx.x;
    const float M  = ml[0];
    const float rL = ml[1];

    if (blockIdx.x < 64) {
        const int b0 = blockIdx.x * 16;
        float4 a = make_float4(0.f, 0.f, 0.f, 0.f);
#pragma unroll 4
        for (int i = 0; i < 16; ++i) {
            const float wsc = __expf(mb[b0 + i] - M) * rL;
            float4 v = *reinterpret_cast<const float4*>(accs + (size_t)(b0 + i) * H + 4 * tid);
            a.x = fmaf(wsc, v.x, a.x);
            a.y = fmaf(wsc, v.y, a.y);
            a.z = fmaf(wsc, v.z, a.z);
            a.w = fmaf(wsc, v.w, a.w);
        }
        atomicAdd(&out[4 * tid + 0], a.x);
        atomicAdd(&out[4 * tid + 1], a.y);
        atomicAdd(&out[4 * tid + 2], a.z);
        atomicAdd(&out[4 * tid + 3], a.w);
    } else {
        const int t0 = (blockIdx.x - 64) * 1024 + 4 * tid;
        float4 sv = *reinterpret_cast<const float4*>(scores + t0);
        float4 wv;
        wv.x = __expf(sv.x - M) * rL;
        wv.y = __expf(sv.y - M) * rL;
        wv.z = __expf(sv.z - M) * rL;
        wv.w = __expf(sv.w - M) * rL;
        *reinterpret_cast<float4*>(wout + t0) = wv;
    }
}

extern "C" void kernel_launch(void* const* d_in, const int* in_sizes, int n_in,
                              void* d_out, int out_size, void* d_ws, size_t ws_size,
                              hipStream_t stream) {
    // inputs: dec_h (1024), enc (T*H), attn_w (2048), attn_b (1)
    // dec_h/attn_b shift all scores by the same constant -> cancels in softmax.
    const float* enc    = (const float*)d_in[1];
    const float* attn_w = (const float*)d_in[2];
    const float* w_enc  = attn_w + 1024;

    float* out  = (float*)d_out;       // [0..H): output vector
    float* wout = (float*)d_out + H;   // [H..H+T): normalized weights

    float* ws     = (float*)d_ws;
    float* ml     = ws + ML_OFF;
    float* mb     = ws + MB_OFF;
    float* lb     = ws + LB_OFF;
    float* scores = ws + SC_OFF;
    float* accs   = ws + ACC_OFF;

    fused_pass1<<<NB1, 256, 0, stream>>>(enc, w_enc, scores, mb, lb, accs);
    reduce2<<<1, 1024, 0, stream>>>(mb, lb, ml, out);
    combine3<<<96, 256, 0, stream>>>(mb, accs, scores, ml, out, wout);
}

// Round 3
// 208.538 us; speedup vs baseline: 1.1954x; 1.0064x over previous
//
#include <hip/hip_runtime.h>
#include <hip/hip_bf16.h>

// (T, H, O) = (32768, 1024, 1024)
constexpr int T = 32768;
constexpr int H = 1024;

constexpr int NB1 = 1024;          // blocks in fused pass 1
constexpr int RPB = T / NB1;       // rows per block = 32
constexpr int CH  = 8;             // rows per chunk (register-resident)

// ws layout (floats)
constexpr int MB_OFF  = 256;               // per-block running max  (NB1)
constexpr int LB_OFF  = MB_OFF + NB1;      // per-block running sum  (NB1)
constexpr int SC_OFF  = 4096;              // raw scores (T)
constexpr int ACC_OFF = SC_OFF + T;        // per-block partial outputs (NB1*H)

// ---------------- Kernel 1: fused scores + online-softmax partial output ----
// 256 threads/block. Thread t owns output columns 4t..4t+3. Block owns 32 rows.
// Each enc element is read from HBM exactly once (held in registers for both
// the dot product and the weighted accumulation).
// Blocks 0..3 also zero d_out[0..H) (poisoned 0xAA; combine2 atomics need 0).
__global__ __launch_bounds__(256) void fused_pass1(
    const float* __restrict__ enc, const float* __restrict__ w_enc,
    float* __restrict__ scores, float* __restrict__ mb, float* __restrict__ lb,
    float* __restrict__ accs, float* __restrict__ out) {
    const int b    = blockIdx.x;
    const int tid  = threadIdx.x;
    const int wave = tid >> 6;
    const int lane = tid & 63;
    const int row0 = b * RPB;

    if (b < 4) out[b * 256 + tid] = 0.f;

    const float4 w4 = *reinterpret_cast<const float4*>(w_enc + 4 * tid);

    __shared__ float red[4][CH];

    float  m = -1e30f, l = 0.f;
    float4 acc = make_float4(0.f, 0.f, 0.f, 0.f);

    for (int c = 0; c < RPB / CH; ++c) {
        const int r0 = row0 + c * CH;
        float4 e[CH];
        float  p[CH];
#pragma unroll
        for (int r = 0; r < CH; ++r) {
            e[r] = *reinterpret_cast<const float4*>(enc + (size_t)(r0 + r) * H + 4 * tid);
            p[r] = e[r].x * w4.x + e[r].y * w4.y + e[r].z * w4.z + e[r].w * w4.w;
        }
        // wave-level butterfly: every lane gets the wave-sum of each row-partial
#pragma unroll
        for (int r = 0; r < CH; ++r) {
#pragma unroll
            for (int off = 32; off; off >>= 1) p[r] += __shfl_xor(p[r], off);
        }
        if (lane == 0) {
#pragma unroll
            for (int r = 0; r < CH; ++r) red[wave][r] = p[r];
        }
        __syncthreads();
        float s[CH];
        float mc = -1e30f;
#pragma unroll
        for (int r = 0; r < CH; ++r) {
            s[r] = red[0][r] + red[1][r] + red[2][r] + red[3][r];
            mc = fmaxf(mc, s[r]);
        }
        __syncthreads();   // red reusable next chunk

        const float mn  = fmaxf(m, mc);
        const float rs  = __expf(m - mn);     // m=-1e30 first pass -> 0
        l *= rs;
        acc.x *= rs; acc.y *= rs; acc.z *= rs; acc.w *= rs;
#pragma unroll
        for (int r = 0; r < CH; ++r) {
            const float wgt = __expf(s[r] - mn);
            l += wgt;
            acc.x = fmaf(wgt, e[r].x, acc.x);
            acc.y = fmaf(wgt, e[r].y, acc.y);
            acc.z = fmaf(wgt, e[r].z, acc.z);
            acc.w = fmaf(wgt, e[r].w, acc.w);
        }
        m = mn;

        if (tid == 0) {
#pragma unroll
            for (int r = 0; r < CH; ++r) scores[r0 + r] = s[r];
        }
    }

    *reinterpret_cast<float4*>(accs + (size_t)b * H + 4 * tid) = acc;
    if (tid == 0) { mb[b] = m; lb[b] = l; }
}

// ---------------- Kernel 2: redundant global (M,L) + combine + weights ------
// Every block recomputes M, L from mb/lb (8 KB, L2-hot) — cheaper than a
// dedicated single-block kernel + extra launch gap.
// blocks 0..63 : out[h] += sum of 16 rescaled partial vectors (atomic)
// blocks 64..95: normalized weights, 1024 t-values each
__global__ __launch_bounds__(256) void combine2(
    const float* __restrict__ mb, const float* __restrict__ lb,
    const float* __restrict__ accs, const float* __restrict__ scores,
    float* __restrict__ out, float* __restrict__ wout) {
    __shared__ float sm[8];
    const int tid  = threadIdx.x;
    const int wave = tid >> 6;
    const int lane = tid & 63;

    float m = fmaxf(fmaxf(mb[tid], mb[tid + 256]),
                    fmaxf(mb[tid + 512], mb[tid + 768]));
#pragma unroll
    for (int off = 32; off; off >>= 1) m = fmaxf(m, __shfl_xor(m, off));
    if (lane == 0) sm[wave] = m;
    __syncthreads();
    const float M = fmaxf(fmaxf(sm[0], sm[1]), fmaxf(sm[2], sm[3]));

    float l = lb[tid]       * __expf(mb[tid]       - M)
            + lb[tid + 256] * __expf(mb[tid + 256] - M)
            + lb[tid + 512] * __expf(mb[tid + 512] - M)
            + lb[tid + 768] * __expf(mb[tid + 768] - M);
#pragma unroll
    for (int off = 32; off; off >>= 1) l += __shfl_xor(l, off);
    if (lane == 0) sm[4 + wave] = l;
    __syncthreads();
    const float rL = 1.f / (sm[4] + sm[5] + sm[6] + sm[7]);

    if (blockIdx.x < 64) {
        const int b0 = blockIdx.x * 16;
        float4 a = make_float4(0.f, 0.f, 0.f, 0.f);
#pragma unroll 4
        for (int i = 0; i < 16; ++i) {
            const float wsc = __expf(mb[b0 + i] - M) * rL;
            float4 v = *reinterpret_cast<const float4*>(accs + (size_t)(b0 + i) * H + 4 * tid);
            a.x = fmaf(wsc, v.x, a.x);
            a.y = fmaf(wsc, v.y, a.y);
            a.z = fmaf(wsc, v.z, a.z);
            a.w = fmaf(wsc, v.w, a.w);
        }
        atomicAdd(&out[4 * tid + 0], a.x);
        atomicAdd(&out[4 * tid + 1], a.y);
        atomicAdd(&out[4 * tid + 2], a.z);
        atomicAdd(&out[4 * tid + 3], a.w);
    } else {
        const int t0 = (blockIdx.x - 64) * 1024 + 4 * tid;
        float4 sv = *reinterpret_cast<const float4*>(scores + t0);
        float4 wv;
        wv.x = __expf(sv.x - M) * rL;
        wv.y = __expf(sv.y - M) * rL;
        wv.z = __expf(sv.z - M) * rL;
        wv.w = __expf(sv.w - M) * rL;
        *reinterpret_cast<float4*>(wout + t0) = wv;
    }
}

extern "C" void kernel_launch(void* const* d_in, const int* in_sizes, int n_in,
                              void* d_out, int out_size, void* d_ws, size_t ws_size,
                              hipStream_t stream) {
    // inputs: dec_h (1024), enc (T*H), attn_w (2048), attn_b (1)
    // dec_h/attn_b shift all scores by the same constant -> cancels in softmax.
    const float* enc    = (const float*)d_in[1];
    const float* attn_w = (const float*)d_in[2];
    const float* w_enc  = attn_w + 1024;

    float* out  = (float*)d_out;       // [0..H): output vector
    float* wout = (float*)d_out + H;   // [H..H+T): normalized weights

    float* ws     = (float*)d_ws;
    float* mb     = ws + MB_OFF;
    float* lb     = ws + LB_OFF;
    float* scores = ws + SC_OFF;
    float* accs   = ws + ACC_OFF;

    fused_pass1<<<NB1, 256, 0, stream>>>(enc, w_enc, scores, mb, lb, accs, out);
    combine2<<<96, 256, 0, stream>>>(mb, lb, accs, scores, out, wout);
}